// Round 22
// baseline (78.474 us; speedup 1.0000x reference)
//
#include <hip/hip_runtime.h>

// Loss = ||corr_norm(W1)-corr_norm(W2)||^2 + ||corr_norm(B1)-corr_norm(B2)||^2
// within_s  ∝ G1_s - 128*P2_s - 16384*m_s m_s^T ; between_s ∝ P2_s = rm^T rm.
//
// Measured: K1≈20.5us (r16), GEMM≈25us (r14; ksplit 11≈12 -> schedule-bound
// m97 ceiling), tail≈32us. Fence-free tail proven (r21: 77.5).
// r22: K1 v7 — 4b x 32d blocks -> RT written in 1KB contiguous row-granules
// (v6 wrote 256B at 16KB stride; DRAM page-locality theory for the 2x gap
// between K1's 20.5us and its ~12us floor).

typedef float f32x2 __attribute__((ext_vector_type(2)));
typedef float f32x4 __attribute__((ext_vector_type(4)));
typedef short bf16x8 __attribute__((ext_vector_type(8)));
typedef unsigned short u16x4 __attribute__((ext_vector_type(4)));

// ---- ws layout (bytes); P1 last so split-K partial count adapts to ws_size ----
static constexpr size_t OFF_RT    = 0;                         // bf16 R_T [2][768][16384]  = 50,331,648
static constexpr size_t OFF_XM    = 50331648;                  // f32 xm [2][128][768]      = 786,432
static constexpr size_t OFF_M     = 51118080;                  // f32 m  [2][768]           = 6,144
static constexpr size_t OFF_RM    = 51124224;                  // bf16 rm_T [2][768][128]   = 393,216
static constexpr size_t OFF_P2    = 51517440;                  // f32 [42][128*128]         = 2,752,512
static constexpr size_t OFF_BPART = 54269952;                  // f32 [672][16]             = 43,008
static constexpr size_t OFF_P1    = 54355968;                  // f32 [42*ksplit][128*128]

__device__ __forceinline__ unsigned int f2bf_u32(float f) {
  union { float f; unsigned int u; } v; v.f = f;
  unsigned int u = v.u;
  unsigned int lsb = (u >> 16) & 1u;
  u += 0x7fffu + lsb;
  return u >> 16;
}

__device__ __forceinline__ void gload_lds16(const void* g, void* l) {
  __builtin_amdgcn_global_load_lds(
      (const __attribute__((address_space(1))) unsigned int*)g,
      (__attribute__((address_space(3))) unsigned int*)l, 16, 0, 0);
}

// ---------------- K1 v7: 4b x 32d blocks, 1KB-contiguous RT row writes ----------------
// grid 1536 = 24 dtiles(32d) x 2 s x 32 bgroups(4b); block 256 = 4 waves.
// Wave j owns b = bg*4+j (borig = 8bg+2j+s). Lane: p=lane&15 -> d-pair, q=lane>>4
// -> n-quad. Phase 1: 8 iters x 4 consecutive-n f32x2 reads (128B segs/16-lane
// group), bf16 x4 packs -> T[32][536] (col = j*128+n); colsums reduced across q
// via shfl_xor(16,32) -> xm direct. Phase 2: thread (r=t>>3, c=t&7 + 8k) copies
// uint4 T[r][c*8] -> RT row (d0+r), col bg*512 + c*8: 1KB/row per block.
__global__ void __launch_bounds__(256) k1_means_convert(const float* __restrict__ x,
                                                        float* __restrict__ xm,
                                                        unsigned short* __restrict__ RT) {
  __shared__ unsigned short T[32][536];
  int bid = blockIdx.x;
  int dt = bid % 24, rest = bid / 24;
  int s = rest & 1, bg = rest >> 1;
  int tid = threadIdx.x, j = tid >> 6, lane = tid & 63;
  int p = lane & 15, q = lane >> 4;
  int d0 = dt * 32;
  int borig = 8 * bg + 2 * j + s;

  const float* xb = x + (size_t)borig * (128 * 768) + d0 + 2 * p;
  float cs0 = 0.f, cs1 = 0.f;
#pragma unroll
  for (int i = 0; i < 8; ++i) {
    int n0 = i * 16 + q * 4;
    f32x2 a0 = *reinterpret_cast<const f32x2*>(xb + (size_t)(n0 + 0) * 768);
    f32x2 a1 = *reinterpret_cast<const f32x2*>(xb + (size_t)(n0 + 1) * 768);
    f32x2 a2 = *reinterpret_cast<const f32x2*>(xb + (size_t)(n0 + 2) * 768);
    f32x2 a3 = *reinterpret_cast<const f32x2*>(xb + (size_t)(n0 + 3) * 768);
    cs0 += a0[0] + a1[0] + a2[0] + a3[0];
    cs1 += a0[1] + a1[1] + a2[1] + a3[1];
    u16x4 p0, p1;
    p0[0] = (unsigned short)f2bf_u32(a0[0]); p0[1] = (unsigned short)f2bf_u32(a1[0]);
    p0[2] = (unsigned short)f2bf_u32(a2[0]); p0[3] = (unsigned short)f2bf_u32(a3[0]);
    p1[0] = (unsigned short)f2bf_u32(a0[1]); p1[1] = (unsigned short)f2bf_u32(a1[1]);
    p1[2] = (unsigned short)f2bf_u32(a2[1]); p1[3] = (unsigned short)f2bf_u32(a3[1]);
    int col = j * 128 + n0;
    *reinterpret_cast<u16x4*>(&T[2 * p + 0][col]) = p0;
    *reinterpret_cast<u16x4*>(&T[2 * p + 1][col]) = p1;
  }
  // reduce colsums across the 4 q-groups (lanes differ in bits 4,5 only)
  cs0 += __shfl_xor(cs0, 16, 64);  cs0 += __shfl_xor(cs0, 32, 64);
  cs1 += __shfl_xor(cs1, 16, 64);  cs1 += __shfl_xor(cs1, 32, 64);
  if (q == 0) {
    int b = bg * 4 + j;
    f32x2 mv; mv[0] = cs0 * (1.f / 128.f); mv[1] = cs1 * (1.f / 128.f);
    *reinterpret_cast<f32x2*>(xm + (size_t)(s * 128 + b) * 768ull + d0 + 2 * p) = mv;
  }
  __syncthreads();

  // phase 2: T -> RT, 1KB per d-row per block
  int r = tid >> 3, cb = tid & 7;
  unsigned short* rtrow = RT + (size_t)s * (768ull * 16384ull)
                             + (size_t)(d0 + r) * 16384ull + (size_t)bg * 512;
#pragma unroll
  for (int k = 0; k < 8; ++k) {
    int c = cb + k * 8;
    uint4 v = *reinterpret_cast<const uint4*>(&T[r][c * 8]);
    *reinterpret_cast<uint4*>(rtrow + c * 8) = v;
  }
}

// ---------------- K2 v2: slice mean + bf16 residual-mean transpose ----------------
__global__ void __launch_bounds__(256) k2_slice_mean(const float* __restrict__ xm,
                                                     float* __restrict__ m,
                                                     unsigned short* __restrict__ rmT) {
  __shared__ float pm[4][64];
  __shared__ float ml[64];
  int s = blockIdx.x / 12, dg = blockIdx.x % 12;
  int t = threadIdx.x;
  int d_loc = t & 63, part = t >> 6;
  int d = dg * 64 + d_loc;
  const float* base = xm + (size_t)s * 128ull * 768ull + d;
  float acc = 0.f;
#pragma unroll 4
  for (int i = 0; i < 32; ++i) acc += base[(size_t)(part * 32 + i) * 768ull];
  pm[part][d_loc] = acc;
  __syncthreads();
  if (t < 64) {
    float mv = (pm[0][t] + pm[1][t] + pm[2][t] + pm[3][t]) * (1.f / 128.f);
    m[s * 768 + dg * 64 + t] = mv;
    ml[t] = mv;
  }
  __syncthreads();
  float mv = ml[d_loc];
  unsigned short* rt = rmT + ((size_t)s * 768ull + d) * 128ull + part * 32;
#pragma unroll 4
  for (int i = 0; i < 32; ++i)
    rt[i] = (unsigned short)f2bf_u32(base[(size_t)(part * 32 + i) * 768ull] - mv);
}

// ---------------- K3: merged A^T A GEMM (big split-K + between), dbuf, diag-skip ----------------
__device__ __forceinline__ void stage_tile(const unsigned short* __restrict__ g, int KP, int k0,
                                           unsigned short* lds, int wave, int lane) {
#pragma unroll
  for (int i = 0; i < 4; ++i) {
    int cb = (i * 4 + wave) * 64;       // wave-uniform chunk base
    int chunk = cb + lane;
    int r = chunk >> 3, sl = chunk & 7;
    int ss = sl ^ (r & 7);              // inverse-swizzled global source
    const unsigned short* src = g + (size_t)r * KP + (k0 + ss * 8);
    gload_lds16(src, lds + (size_t)cb * 8);
  }
}

__device__ __forceinline__ bf16x8 read_frag(const unsigned short* lds, int row, int slot) {
  int chunk = row * 8 + (slot ^ (row & 7));   // swizzled read
  return *reinterpret_cast<const bf16x8*>(lds + chunk * 8);
}

__device__ __forceinline__ void tp2tile(int tp, int& td, int& te) {
  td = 0; int t2 = tp;
  while (t2 >= 6 - td) { t2 -= 6 - td; ++td; }
  te = td + t2;
}

__global__ void __launch_bounds__(256) gemm_ata(const unsigned short* __restrict__ Rbig,
                                                const unsigned short* __restrict__ rmT,
                                                float* __restrict__ P1, float* __restrict__ P2,
                                                int ksplit) {
  __shared__ unsigned short Ta[2][128 * 64];
  __shared__ unsigned short Tb[2][128 * 64];
  int bid = blockIdx.x;
  const unsigned short* R; size_t slice_stride; int KP;
  int rest, step0, step1; float* pout;
  if (bid < 42 * ksplit) {                       // big GEMM: K=16384, split-K
    R = Rbig; slice_stride = 768ull * 16384ull; KP = 16384;
    int c = bid % ksplit; rest = bid / ksplit;
    step0 = (256 * c) / ksplit; step1 = (256 * (c + 1)) / ksplit;
    pout = P1 + (size_t)bid * (128 * 128);
  } else {                                       // between GEMM: K=128
    int b2 = bid - 42 * ksplit;
    R = rmT; slice_stride = 768ull * 128ull; KP = 128;
    rest = b2; step0 = 0; step1 = 2;
    pout = P2 + (size_t)b2 * (128 * 128);
  }
  int s = rest & 1; int tp = rest >> 1;
  int td, te; tp2tile(tp, td, te);
  bool diag = (td == te);
  const unsigned short* Ra = R + (size_t)s * slice_stride + (size_t)(td * 128) * KP;
  const unsigned short* Rb = R + (size_t)s * slice_stride + (size_t)(te * 128) * KP;
  int tid = threadIdx.x, wave = tid >> 6, lane = tid & 63;
  int m_off = (wave >> 1) * 64, n_off = (wave & 1) * 64;
  int row_a = m_off + (lane & 15), row_b = n_off + (lane & 15);
  f32x4 acc[4][4];
#pragma unroll
  for (int i = 0; i < 4; ++i)
#pragma unroll
    for (int j = 0; j < 4; ++j) { acc[i][j][0]=0.f; acc[i][j][1]=0.f; acc[i][j][2]=0.f; acc[i][j][3]=0.f; }

  // prologue: stage first tile
  stage_tile(Ra, KP, step0 * 64, Ta[0], wave, lane);
  if (!diag) stage_tile(Rb, KP, step0 * 64, Tb[0], wave, lane);
  __syncthreads();

  int cur = 0;
  for (int kt = step0; kt < step1; ++kt) {
    if (kt + 1 < step1) {                 // prefetch next tile (overlaps MFMA)
      stage_tile(Ra, KP, (kt + 1) * 64, Ta[cur ^ 1], wave, lane);
      if (!diag) stage_tile(Rb, KP, (kt + 1) * 64, Tb[cur ^ 1], wave, lane);
    }
    const unsigned short* Bsrc = diag ? Ta[cur] : Tb[cur];
#pragma unroll
    for (int ks = 0; ks < 2; ++ks) {
      bf16x8 a[4], b[4];
      int slot = ks * 4 + (lane >> 4);
#pragma unroll
      for (int mi = 0; mi < 4; ++mi) a[mi] = read_frag(Ta[cur], row_a + mi * 16, slot);
#pragma unroll
      for (int ni = 0; ni < 4; ++ni) b[ni] = read_frag(Bsrc, row_b + ni * 16, slot);
#pragma unroll
      for (int mi = 0; mi < 4; ++mi)
#pragma unroll
        for (int ni = 0; ni < 4; ++ni)
          acc[mi][ni] = __builtin_amdgcn_mfma_f32_16x16x32_bf16(a[mi], b[ni], acc[mi][ni], 0, 0, 0);
    }
    __syncthreads();   // staged tile landed + all reads of buf[cur] done
    cur ^= 1;
  }
  int hi = lane >> 4, lo = lane & 15;
#pragma unroll
  for (int mi = 0; mi < 4; ++mi)
#pragma unroll
    for (int ni = 0; ni < 4; ++ni)
#pragma unroll
      for (int r = 0; r < 4; ++r) {
        int rr = m_off + mi * 16 + hi * 4 + r;
        int cc = n_off + ni * 16 + lo;
        pout[rr * 128 + cc] = acc[mi][ni][r];
      }
}

// ---------------- K5: 10-way partial sums, grid 672, compile-time KS, NO fence ----------------
template <int KS>
__global__ void __launch_bounds__(256) k5_elem(const float* __restrict__ P1,
                                               const float* __restrict__ P2,
                                               const float* __restrict__ m,
                                               float* __restrict__ bpart, int ksplit_rt) {
  __shared__ float red[4][10];
  int bid = blockIdx.x;                 // 0..671
  int tp = bid >> 5, sub = bid & 31;
  int td, te; tp2tile(tp, td, te);
  bool diagTile = (td == te);
  float mult = diagTile ? 1.0f : 2.0f;
  int t = threadIdx.x;
  int lane = t & 63, w = t >> 6;
  int ksplit = (KS > 0) ? KS : ksplit_rt;
  float v[10];
#pragma unroll
  for (int j = 0; j < 10; ++j) v[j] = 0.f;

#pragma unroll
  for (int k = 0; k < 2; ++k) {
    int idx = sub * 512 + k * 256 + t;   // 0..16383 within tile
    int r = idx >> 7, cc = idx & 127;
    int d = td * 128 + r, e = te * 128 + cc;
    float W[2], B[2];
#pragma unroll
    for (int s = 0; s < 2; ++s) {
      const float* base1 = P1 + (size_t)((tp * 2 + s) * ksplit) * 16384ull + idx;
      float g1 = 0.f;
#pragma unroll
      for (int c6 = 0; c6 < ((KS > 0) ? KS : 16); ++c6) {
        if (KS > 0 || c6 < ksplit) g1 += base1[(size_t)c6 * 16384ull];
      }
      float p2v = P2[(size_t)(tp * 2 + s) * 16384ull + idx];
      W[s] = g1 - 128.0f * p2v - 16384.0f * m[s * 768 + d] * m[s * 768 + e];
      B[s] = p2v;
    }
    v[0] += W[0] * W[0] * mult;  v[1] += W[1] * W[1] * mult;  v[2] += W[0] * W[1] * mult;
    v[3] += B[0] * B[0] * mult;  v[4] += B[1] * B[1] * mult;  v[5] += B[0] * B[1] * mult;
    if (diagTile && r == cc) {
      v[6] += W[0] * W[0];  v[7] += W[1] * W[1];
      v[8] += B[0] * B[0];  v[9] += B[1] * B[1];
    }
  }
#pragma unroll
  for (int off = 32; off; off >>= 1)
#pragma unroll
    for (int j = 0; j < 10; ++j) v[j] += __shfl_down(v[j], off, 64);
  if (lane == 0)
#pragma unroll
    for (int j = 0; j < 10; ++j) red[w][j] = v[j];
  __syncthreads();
  if (t < 10) bpart[bid * 16 + t] = red[0][t] + red[1][t] + red[2][t] + red[3][t];
}

// ---------------- K6: final reduce + normalized combine ----------------
__global__ void __launch_bounds__(256) k6_final(const float* __restrict__ bpart,
                                                float* __restrict__ out) {
  __shared__ float red[4][10];
  float acc[10];
#pragma unroll
  for (int j = 0; j < 10; ++j) acc[j] = 0.f;
  for (int i = threadIdx.x; i < 672; i += 256)
#pragma unroll
    for (int j = 0; j < 10; ++j) acc[j] += bpart[i * 16 + j];
  int lane = threadIdx.x & 63, w = threadIdx.x >> 6;
#pragma unroll
  for (int off = 32; off; off >>= 1)
#pragma unroll
    for (int j = 0; j < 10; ++j) acc[j] += __shfl_down(acc[j], off, 64);
  if (lane == 0)
#pragma unroll
    for (int j = 0; j < 10; ++j) red[w][j] = acc[j];
  __syncthreads();
  if (threadIdx.x == 0) {
    float S[10];
#pragma unroll
    for (int j = 0; j < 10; ++j) S[j] = red[0][j] + red[1][j] + red[2][j] + red[3][j];
    float lw = S[0] / S[6] + S[1] / S[7] - 2.0f * S[2] / sqrtf(S[6] * S[7]);
    float lb = S[3] / S[8] + S[4] / S[9] - 2.0f * S[5] / sqrtf(S[8] * S[9]);
    out[0] = lw + lb;
  }
}

extern "C" void kernel_launch(void* const* d_in, const int* in_sizes, int n_in,
                              void* d_out, int out_size, void* d_ws, size_t ws_size,
                              hipStream_t stream) {
  const float* x = (const float*)d_in[0];
  char* ws = (char*)d_ws;
  unsigned short* RT  = (unsigned short*)(ws + OFF_RT);
  float* xm           = (float*)(ws + OFF_XM);
  float* m            = (float*)(ws + OFF_M);
  unsigned short* rmT = (unsigned short*)(ws + OFF_RM);
  float* P2           = (float*)(ws + OFF_P2);
  float* bpart        = (float*)(ws + OFF_BPART);
  float* P1           = (float*)(ws + OFF_P1);
  float* out          = (float*)d_out;

  // split-K = 11: 42*11+42 = 504 blocks <= 512 co-resident (2 blocks/CU at 64KB LDS)
  size_t availP1 = (ws_size > OFF_P1) ? (ws_size - OFF_P1) : 0;
  int ksplit = (int)(availP1 / (42ull * 128 * 128 * 4));
  if (ksplit > 11) ksplit = 11;
  if (ksplit < 1) ksplit = 1;

  hipLaunchKernelGGL(k1_means_convert, dim3(1536), dim3(256), 0, stream, x, xm, RT);
  hipLaunchKernelGGL(k2_slice_mean, dim3(24), dim3(256), 0, stream, xm, m, rmT);
  hipLaunchKernelGGL(gemm_ata, dim3(42 * ksplit + 42), dim3(256), 0, stream,
                     RT, rmT, P1, P2, ksplit);
  if (ksplit == 11) {
    hipLaunchKernelGGL((k5_elem<11>), dim3(672), dim3(256), 0, stream,
                       P1, P2, m, bpart, ksplit);
  } else {
    hipLaunchKernelGGL((k5_elem<0>), dim3(672), dim3(256), 0, stream,
                       P1, P2, m, bpart, ksplit);
  }
  hipLaunchKernelGGL(k6_final, dim3(1), dim3(256), 0, stream, bpart, out);
}

// Round 24
// 71.043 us; speedup vs baseline: 1.1046x; 1.1046x over previous
//
#include <hip/hip_runtime.h>

// Loss = ||corr_norm(W1)-corr_norm(W2)||^2 + ||corr_norm(B1)-corr_norm(B2)||^2
// within_s  ∝ G1_s - 128*P2_s - 16384*m_s m_s^T ; between_s ∝ P2_s = rm^T rm.
//
// Measured: K1≈20.5us (3 rewrites ~equal -> keep v6), GEMM≈25us, fence-free
// tail (r21: 77.5 best). r24 theory: GEMM is L3-BW-bound (288MB panel
// re-reads / 25us = 11.5 TB/s). Test: ksplit=12 -> nbig=504=8*63, XCD
// swizzle logical=(bid&7)*63+(bid>>3) bijective; one (s,c) group's 21
// tiles (6 panel-chunks ~2.3MB, L2-fit) run contiguously on one XCD.
// (r23's build had the swizzle DEAD: nbig was 462 at ksplit=11.)
// P1 written at canonical (tp,s,c) index so K5 unchanged.

typedef float f32x2 __attribute__((ext_vector_type(2)));
typedef float f32x4 __attribute__((ext_vector_type(4)));
typedef short bf16x8 __attribute__((ext_vector_type(8)));
typedef unsigned short u16x4 __attribute__((ext_vector_type(4)));

// ---- ws layout (bytes); P1 last so split-K partial count adapts to ws_size ----
static constexpr size_t OFF_RT    = 0;                         // bf16 R_T [2][768][16384]  = 50,331,648
static constexpr size_t OFF_XM    = 50331648;                  // f32 xm [2][128][768]      = 786,432
static constexpr size_t OFF_M     = 51118080;                  // f32 m  [2][768]           = 6,144
static constexpr size_t OFF_RM    = 51124224;                  // bf16 rm_T [2][768][128]   = 393,216
static constexpr size_t OFF_P2    = 51517440;                  // f32 [42][128*128]         = 2,752,512
static constexpr size_t OFF_BPART = 54269952;                  // f32 [672][16]             = 43,008
static constexpr size_t OFF_P1    = 54355968;                  // f32 [42*ksplit][128*128]

__device__ __forceinline__ unsigned int f2bf_u32(float f) {
  union { float f; unsigned int u; } v; v.f = f;
  unsigned int u = v.u;
  unsigned int lsb = (u >> 16) & 1u;
  u += 0x7fffu + lsb;
  return u >> 16;
}

__device__ __forceinline__ void gload_lds16(const void* g, void* l) {
  __builtin_amdgcn_global_load_lds(
      (const __attribute__((address_space(1))) unsigned int*)g,
      (__attribute__((address_space(3))) unsigned int*)l, 16, 0, 0);
}

// ---------------- K1 v6: LDS bf16 transpose-convert + f32 register means ----------------
__global__ void __launch_bounds__(256) k1_means_convert(const float* __restrict__ x,
                                                        float* __restrict__ xm,
                                                        unsigned short* __restrict__ RT) {
  __shared__ unsigned short T[128][130];
  __shared__ float pm[4][128];
  int bid = blockIdx.x;
  int dt = bid % 6, borig = bid / 6;
  int s = borig & 1, b = borig >> 1;
  int tid = threadIdx.x, w = tid >> 6, lane = tid & 63;

  const float* xb = x + (size_t)borig * (128 * 768) + dt * 128 + 2 * lane;
  float cs0 = 0.f, cs1 = 0.f;
#pragma unroll
  for (int g = 0; g < 8; ++g) {
    int n0 = w * 32 + g * 4;
    f32x2 a0 = *reinterpret_cast<const f32x2*>(xb + (size_t)(n0 + 0) * 768);
    f32x2 a1 = *reinterpret_cast<const f32x2*>(xb + (size_t)(n0 + 1) * 768);
    f32x2 a2 = *reinterpret_cast<const f32x2*>(xb + (size_t)(n0 + 2) * 768);
    f32x2 a3 = *reinterpret_cast<const f32x2*>(xb + (size_t)(n0 + 3) * 768);
    cs0 += a0[0] + a1[0] + a2[0] + a3[0];
    cs1 += a0[1] + a1[1] + a2[1] + a3[1];
    u16x4 p0, p1;
    p0[0] = (unsigned short)f2bf_u32(a0[0]); p0[1] = (unsigned short)f2bf_u32(a1[0]);
    p0[2] = (unsigned short)f2bf_u32(a2[0]); p0[3] = (unsigned short)f2bf_u32(a3[0]);
    p1[0] = (unsigned short)f2bf_u32(a0[1]); p1[1] = (unsigned short)f2bf_u32(a1[1]);
    p1[2] = (unsigned short)f2bf_u32(a2[1]); p1[3] = (unsigned short)f2bf_u32(a3[1]);
    *reinterpret_cast<u16x4*>(&T[2 * lane + 0][n0]) = p0;
    *reinterpret_cast<u16x4*>(&T[2 * lane + 1][n0]) = p1;
  }
  *reinterpret_cast<f32x2*>(&pm[w][2 * lane]) = f32x2{cs0, cs1};
  __syncthreads();

  if (tid < 128) {
    float mv = (pm[0][tid] + pm[1][tid] + pm[2][tid] + pm[3][tid]) * (1.f / 128.f);
    xm[((size_t)(s * 128 + b)) * 768ull + dt * 128 + tid] = mv;
  }

  int half = lane >> 5;
  int nb = (lane & 31) * 4;
  unsigned short* rtbase = RT + (size_t)s * (768ull * 16384ull) + (size_t)(b * 128 + nb);
#pragma unroll
  for (int i = 0; i < 16; ++i) {
    int d_loc = w * 32 + 2 * i + half;
    uint2 v = *reinterpret_cast<const uint2*>(&T[d_loc][nb]);
    *reinterpret_cast<uint2*>(rtbase + (size_t)(dt * 128 + d_loc) * 16384ull) = v;
  }
}

// ---------------- K2 v2: slice mean + bf16 residual-mean transpose ----------------
__global__ void __launch_bounds__(256) k2_slice_mean(const float* __restrict__ xm,
                                                     float* __restrict__ m,
                                                     unsigned short* __restrict__ rmT) {
  __shared__ float pm[4][64];
  __shared__ float ml[64];
  int s = blockIdx.x / 12, dg = blockIdx.x % 12;
  int t = threadIdx.x;
  int d_loc = t & 63, part = t >> 6;
  int d = dg * 64 + d_loc;
  const float* base = xm + (size_t)s * 128ull * 768ull + d;
  float acc = 0.f;
#pragma unroll 4
  for (int i = 0; i < 32; ++i) acc += base[(size_t)(part * 32 + i) * 768ull];
  pm[part][d_loc] = acc;
  __syncthreads();
  if (t < 64) {
    float mv = (pm[0][t] + pm[1][t] + pm[2][t] + pm[3][t]) * (1.f / 128.f);
    m[s * 768 + dg * 64 + t] = mv;
    ml[t] = mv;
  }
  __syncthreads();
  float mv = ml[d_loc];
  unsigned short* rt = rmT + ((size_t)s * 768ull + d) * 128ull + part * 32;
#pragma unroll 4
  for (int i = 0; i < 32; ++i)
    rt[i] = (unsigned short)f2bf_u32(base[(size_t)(part * 32 + i) * 768ull] - mv);
}

// ---------------- K3: merged A^T A GEMM, dbuf, diag-skip, XCD-grouped block order ----------------
__device__ __forceinline__ void stage_tile(const unsigned short* __restrict__ g, int KP, int k0,
                                           unsigned short* lds, int wave, int lane) {
#pragma unroll
  for (int i = 0; i < 4; ++i) {
    int cb = (i * 4 + wave) * 64;       // wave-uniform chunk base
    int chunk = cb + lane;
    int r = chunk >> 3, sl = chunk & 7;
    int ss = sl ^ (r & 7);              // inverse-swizzled global source
    const unsigned short* src = g + (size_t)r * KP + (k0 + ss * 8);
    gload_lds16(src, lds + (size_t)cb * 8);
  }
}

__device__ __forceinline__ bf16x8 read_frag(const unsigned short* lds, int row, int slot) {
  int chunk = row * 8 + (slot ^ (row & 7));   // swizzled read
  return *reinterpret_cast<const bf16x8*>(lds + chunk * 8);
}

__device__ __forceinline__ void tp2tile(int tp, int& td, int& te) {
  td = 0; int t2 = tp;
  while (t2 >= 6 - td) { t2 -= 6 - td; ++td; }
  te = td + t2;
}

__global__ void __launch_bounds__(256) gemm_ata(const unsigned short* __restrict__ Rbig,
                                                const unsigned short* __restrict__ rmT,
                                                float* __restrict__ P1, float* __restrict__ P2,
                                                int ksplit) {
  __shared__ unsigned short Ta[2][128 * 64];
  __shared__ unsigned short Tb[2][128 * 64];
  int bid = blockIdx.x;
  int nbig = 42 * ksplit;
  const unsigned short* R; size_t slice_stride; int KP;
  int s, tp, step0, step1; float* pout;
  if (bid < nbig) {
    // XCD-grouped order (active when ksplit=12: nbig=504=8*63). HW dispatch
    // round-robins raw bid over 8 XCDs, so logical=(bid&7)*63+(bid>>3) puts
    // logical 0..62 on XCD0, 63..125 on XCD1, ... Each (s,c) group of 21
    // tiles (logical/21) then runs on ~one XCD; its 6 panel-chunks
    // (12 x 2 x 128x1365x2B ~ 2.3MB total) stay L2-resident there.
    int logical;
    if (nbig == 504) logical = (bid & 7) * 63 + (bid >> 3);
    else             logical = bid;
    int g = logical / 21; tp = logical % 21;
    s = g & 1; int c = g >> 1;
    R = Rbig; slice_stride = 768ull * 16384ull; KP = 16384;
    step0 = (256 * c) / ksplit; step1 = (256 * (c + 1)) / ksplit;
    pout = P1 + (size_t)((tp * 2 + s) * ksplit + c) * (128 * 128);  // canonical for K5
  } else {                                       // between GEMM: K=128
    int b2 = bid - nbig;
    R = rmT; slice_stride = 768ull * 128ull; KP = 128;
    s = b2 & 1; tp = b2 >> 1; step0 = 0; step1 = 2;
    pout = P2 + (size_t)b2 * (128 * 128);
  }
  int td, te; tp2tile(tp, td, te);
  bool diag = (td == te);
  const unsigned short* Ra = R + (size_t)s * slice_stride + (size_t)(td * 128) * KP;
  const unsigned short* Rb = R + (size_t)s * slice_stride + (size_t)(te * 128) * KP;
  int tid = threadIdx.x, wave = tid >> 6, lane = tid & 63;
  int m_off = (wave >> 1) * 64, n_off = (wave & 1) * 64;
  int row_a = m_off + (lane & 15), row_b = n_off + (lane & 15);
  f32x4 acc[4][4];
#pragma unroll
  for (int i = 0; i < 4; ++i)
#pragma unroll
    for (int j = 0; j < 4; ++j) { acc[i][j][0]=0.f; acc[i][j][1]=0.f; acc[i][j][2]=0.f; acc[i][j][3]=0.f; }

  // prologue: stage first tile
  stage_tile(Ra, KP, step0 * 64, Ta[0], wave, lane);
  if (!diag) stage_tile(Rb, KP, step0 * 64, Tb[0], wave, lane);
  __syncthreads();

  int cur = 0;
  for (int kt = step0; kt < step1; ++kt) {
    if (kt + 1 < step1) {                 // prefetch next tile (overlaps MFMA)
      stage_tile(Ra, KP, (kt + 1) * 64, Ta[cur ^ 1], wave, lane);
      if (!diag) stage_tile(Rb, KP, (kt + 1) * 64, Tb[cur ^ 1], wave, lane);
    }
    const unsigned short* Bsrc = diag ? Ta[cur] : Tb[cur];
#pragma unroll
    for (int ks = 0; ks < 2; ++ks) {
      bf16x8 a[4], b[4];
      int slot = ks * 4 + (lane >> 4);
#pragma unroll
      for (int mi = 0; mi < 4; ++mi) a[mi] = read_frag(Ta[cur], row_a + mi * 16, slot);
#pragma unroll
      for (int ni = 0; ni < 4; ++ni) b[ni] = read_frag(Bsrc, row_b + ni * 16, slot);
#pragma unroll
      for (int mi = 0; mi < 4; ++mi)
#pragma unroll
        for (int ni = 0; ni < 4; ++ni)
          acc[mi][ni] = __builtin_amdgcn_mfma_f32_16x16x32_bf16(a[mi], b[ni], acc[mi][ni], 0, 0, 0);
    }
    __syncthreads();   // staged tile landed + all reads of buf[cur] done
    cur ^= 1;
  }
  int hi = lane >> 4, lo = lane & 15;
#pragma unroll
  for (int mi = 0; mi < 4; ++mi)
#pragma unroll
    for (int ni = 0; ni < 4; ++ni)
#pragma unroll
      for (int r = 0; r < 4; ++r) {
        int rr = m_off + mi * 16 + hi * 4 + r;
        int cc = n_off + ni * 16 + lo;
        pout[rr * 128 + cc] = acc[mi][ni][r];
      }
}

// ---------------- K5: 10-way partial sums, grid 672, compile-time KS, NO fence ----------------
template <int KS>
__global__ void __launch_bounds__(256) k5_elem(const float* __restrict__ P1,
                                               const float* __restrict__ P2,
                                               const float* __restrict__ m,
                                               float* __restrict__ bpart, int ksplit_rt) {
  __shared__ float red[4][10];
  int bid = blockIdx.x;                 // 0..671
  int tp = bid >> 5, sub = bid & 31;
  int td, te; tp2tile(tp, td, te);
  bool diagTile = (td == te);
  float mult = diagTile ? 1.0f : 2.0f;
  int t = threadIdx.x;
  int lane = t & 63, w = t >> 6;
  int ksplit = (KS > 0) ? KS : ksplit_rt;
  float v[10];
#pragma unroll
  for (int j = 0; j < 10; ++j) v[j] = 0.f;

#pragma unroll
  for (int k = 0; k < 2; ++k) {
    int idx = sub * 512 + k * 256 + t;   // 0..16383 within tile
    int r = idx >> 7, cc = idx & 127;
    int d = td * 128 + r, e = te * 128 + cc;
    float W[2], B[2];
#pragma unroll
    for (int s = 0; s < 2; ++s) {
      const float* base1 = P1 + (size_t)((tp * 2 + s) * ksplit) * 16384ull + idx;
      float g1 = 0.f;
#pragma unroll
      for (int c6 = 0; c6 < ((KS > 0) ? KS : 16); ++c6) {
        if (KS > 0 || c6 < ksplit) g1 += base1[(size_t)c6 * 16384ull];
      }
      float p2v = P2[(size_t)(tp * 2 + s) * 16384ull + idx];
      W[s] = g1 - 128.0f * p2v - 16384.0f * m[s * 768 + d] * m[s * 768 + e];
      B[s] = p2v;
    }
    v[0] += W[0] * W[0] * mult;  v[1] += W[1] * W[1] * mult;  v[2] += W[0] * W[1] * mult;
    v[3] += B[0] * B[0] * mult;  v[4] += B[1] * B[1] * mult;  v[5] += B[0] * B[1] * mult;
    if (diagTile && r == cc) {
      v[6] += W[0] * W[0];  v[7] += W[1] * W[1];
      v[8] += B[0] * B[0];  v[9] += B[1] * B[1];
    }
  }
#pragma unroll
  for (int off = 32; off; off >>= 1)
#pragma unroll
    for (int j = 0; j < 10; ++j) v[j] += __shfl_down(v[j], off, 64);
  if (lane == 0)
#pragma unroll
    for (int j = 0; j < 10; ++j) red[w][j] = v[j];
  __syncthreads();
  if (t < 10) bpart[bid * 16 + t] = red[0][t] + red[1][t] + red[2][t] + red[3][t];
}

// ---------------- K6: final reduce + normalized combine ----------------
__global__ void __launch_bounds__(256) k6_final(const float* __restrict__ bpart,
                                                float* __restrict__ out) {
  __shared__ float red[4][10];
  float acc[10];
#pragma unroll
  for (int j = 0; j < 10; ++j) acc[j] = 0.f;
  for (int i = threadIdx.x; i < 672; i += 256)
#pragma unroll
    for (int j = 0; j < 10; ++j) acc[j] += bpart[i * 16 + j];
  int lane = threadIdx.x & 63, w = threadIdx.x >> 6;
#pragma unroll
  for (int off = 32; off; off >>= 1)
#pragma unroll
    for (int j = 0; j < 10; ++j) acc[j] += __shfl_down(acc[j], off, 64);
  if (lane == 0)
#pragma unroll
    for (int j = 0; j < 10; ++j) red[w][j] = acc[j];
  __syncthreads();
  if (threadIdx.x == 0) {
    float S[10];
#pragma unroll
    for (int j = 0; j < 10; ++j) S[j] = red[0][j] + red[1][j] + red[2][j] + red[3][j];
    float lw = S[0] / S[6] + S[1] / S[7] - 2.0f * S[2] / sqrtf(S[6] * S[7]);
    float lb = S[3] / S[8] + S[4] / S[9] - 2.0f * S[5] / sqrtf(S[8] * S[9]);
    out[0] = lw + lb;
  }
}

extern "C" void kernel_launch(void* const* d_in, const int* in_sizes, int n_in,
                              void* d_out, int out_size, void* d_ws, size_t ws_size,
                              hipStream_t stream) {
  const float* x = (const float*)d_in[0];
  char* ws = (char*)d_ws;
  unsigned short* RT  = (unsigned short*)(ws + OFF_RT);
  float* xm           = (float*)(ws + OFF_XM);
  float* m            = (float*)(ws + OFF_M);
  unsigned short* rmT = (unsigned short*)(ws + OFF_RM);
  float* P2           = (float*)(ws + OFF_P2);
  float* bpart        = (float*)(ws + OFF_BPART);
  float* P1           = (float*)(ws + OFF_P1);
  float* out          = (float*)d_out;

  // split-K = 12: nbig = 504 = 8*63 -> XCD swizzle bijective & ACTIVE
  size_t availP1 = (ws_size > OFF_P1) ? (ws_size - OFF_P1) : 0;
  int ksplit = (int)(availP1 / (42ull * 128 * 128 * 4));
  if (ksplit > 12) ksplit = 12;
  if (ksplit < 1) ksplit = 1;

  hipLaunchKernelGGL(k1_means_convert, dim3(1536), dim3(256), 0, stream, x, xm, RT);
  hipLaunchKernelGGL(k2_slice_mean, dim3(24), dim3(256), 0, stream, xm, m, rmT);
  hipLaunchKernelGGL(gemm_ata, dim3(42 * ksplit + 42), dim3(256), 0, stream,
                     RT, rmT, P1, P2, ksplit);
  if (ksplit == 12) {
    hipLaunchKernelGGL((k5_elem<12>), dim3(672), dim3(256), 0, stream,
                       P1, P2, m, bpart, ksplit);
  } else if (ksplit == 11) {
    hipLaunchKernelGGL((k5_elem<11>), dim3(672), dim3(256), 0, stream,
                       P1, P2, m, bpart, ksplit);
  } else {
    hipLaunchKernelGGL((k5_elem<0>), dim3(672), dim3(256), 0, stream,
                       P1, P2, m, bpart, ksplit);
  }
  hipLaunchKernelGGL(k6_final, dim3(1), dim3(256), 0, stream, bpart, out);
}